// Round 12
// baseline (193.063 us; speedup 1.0000x reference)
//
#include <hip/hip_runtime.h>

#define N_NODES 100000
#define N_EDGES 640000
#define DIN 128
#define HDIM 128
#define DOUT 64

typedef __attribute__((ext_vector_type(4))) float f32x4;
typedef __attribute__((ext_vector_type(8))) short bf16x8;

// ---------- bf16 helpers ----------
__device__ inline unsigned short f2bf(float x) {
    unsigned u = __float_as_uint(x);
    unsigned r = (u + 0x7fffu + ((u >> 16) & 1u)) >> 16;   // RNE
    return (unsigned short)r;
}
__device__ inline void unpack2(unsigned u, float& f0, float& f1) {
    f0 = __uint_as_float(u << 16);
    f1 = __uint_as_float(u & 0xffff0000u);
}

struct PrepPtrs {
    const float *g[3], *b[3], *m[3], *v[3];
    const float *W[3];                         // weights f32 [128][COUT]
    float *tW[3];
    unsigned short *wt[3];                     // bf16 [COUT][128]
};

// ================ combo: edge-rank histogram + BN fold/tW + weight transform ================
__global__ void combo_prep_kernel(const int* __restrict__ ei, int* __restrict__ cnt,
                                  int* __restrict__ rank, int ne, int gE, PrepPtrs p) {
    int bid = blockIdx.x, tid = threadIdx.x;
    if (bid < gE) {
        int e = bid * 256 + tid;
        if (e < ne) rank[e] = atomicAdd(&cnt[ei[ne + e]], 1);
        return;
    }
    if (bid < gE + 3) {
        __shared__ float sh_s[128];
        int l = bid - gE;
        if (tid < 128) {
            float s  = p.g[l][tid] * rsqrtf(p.v[l][tid] + 1e-5f);
            sh_s[tid] = p.b[l][tid] - p.m[l][tid] * s;
        }
        __syncthreads();
        int cout = (l == 2) ? DOUT : HDIM;
        if (tid < cout) {
            float acc = 0.f;
            for (int k = 0; k < 128; ++k) acc += sh_s[k] * p.W[l][k * cout + tid];
            p.tW[l][tid] = acc;
        }
        return;
    }
    {
        int idx0 = bid - gE - 3;          // 64 blocks per layer
        int l = idx0 >> 6;
        int cout = (l == 2) ? DOUT : HDIM;
        int idx = (idx0 & 63) * 256 + tid;   // k*cout + c
        if (idx >= 128 * cout) return;
        int k = idx / cout, c = idx % cout;
        float sc = p.g[l][k] * rsqrtf(p.v[l][k] + 1e-5f);
        p.wt[l][c * 128 + k] = f2bf(p.W[l][idx] * sc);
    }
}

// ================ single-pass scan (decoupled lookback) + dinv + rng ================
// 98 blocks x 1024 threads; all co-resident (<=256 CUs, sole dispatch) -> spin is safe.
// aggflag[] zeroed by the same memset as cnt; block b publishes agg+1.
__global__ __launch_bounds__(1024) void scan_fused_kernel(
    const int* __restrict__ cnt, int* __restrict__ off, float* __restrict__ dinv,
    int2* __restrict__ rng, int* __restrict__ aggflag, int n)
{
    __shared__ int sm[1024];
    __shared__ int red[2];
    int tid = threadIdx.x, b = blockIdx.x;
    int i = b * 1024 + tid;
    int v = (i < n) ? cnt[i] : 0;
    sm[tid] = v;
    __syncthreads();
    for (int d = 1; d < 1024; d <<= 1) {
        int t = (tid >= d) ? sm[tid - d] : 0;
        __syncthreads();
        sm[tid] += t;
        __syncthreads();
    }
    // publish this block's aggregate (device-scope)
    if (tid == 1023) {
        __threadfence();
        atomicExch(&aggflag[b], sm[1023] + 1);
    }
    // lookback: thread t < b polls aggflag[t]
    int pv = 0;
    if (tid < b) {
        int val;
        do { val = atomicAdd(&aggflag[tid], 0); } while (val == 0);
        pv = val - 1;
    }
    #pragma unroll
    for (int o = 32; o > 0; o >>= 1) pv += __shfl_down(pv, o);
    if (tid == 0)  red[0] = pv;
    if (tid == 64) red[1] = pv;
    __syncthreads();
    int prefix = red[0] + red[1];          // b < 98 < 128, only waves 0-1 matter

    if (i < n) {
        int o = sm[tid] - v + prefix;      // exclusive global offset
        off[i] = o;
        rng[i] = make_int2(o, o + v);
        dinv[i] = rsqrtf((float)v + 1.0f); // +1 self loop
    }
}

// ================ merged: CSR fill (atomic-free) + layer-1 MFMA GEMM ================
// blocks [0, gT):        T[N][128] = bf16(X) @ Wt^T + tW
// blocks [gT, gT+gE):    csr[off[d]+rank[e]] = {src, coef}
template<int COUT>
__global__ __launch_bounds__(256) void fill_gemm_kernel(
    const int* __restrict__ ei, const float* __restrict__ dinv,
    const int* __restrict__ off, const int* __restrict__ rank,
    int2* __restrict__ csr, int ne, int gT,
    const float* __restrict__ X, const unsigned short* __restrict__ Wt,
    const float* __restrict__ tW, unsigned short* __restrict__ T, int nrows)
{
    constexpr int LDT = 136;
    __shared__ unsigned short xs[64 * LDT];
    __shared__ unsigned short ws[COUT * LDT];

    int tid = threadIdx.x;

    if (blockIdx.x >= gT) {
        // ---- fill path (block-uniform branch) ----
        int e = (blockIdx.x - gT) * 256 + tid;
        if (e < ne) {
            int s = ei[e], d = ei[ne + e];
            int2 ent;
            ent.x = s;
            ent.y = __float_as_int(dinv[s] * dinv[d]);
            csr[off[d] + rank[e]] = ent;
        }
        return;
    }

    // ---- GEMM path ----
    int wave = tid >> 6, lane = tid & 63;
    int row0 = blockIdx.x * 64;

    {
        const uint4* src = (const uint4*)Wt;
        #pragma unroll
        for (int it = 0; it < COUT / 16; ++it) {
            int idx = tid + it * 256;
            int r = idx >> 4, c8 = idx & 15;
            uint4 v = src[idx];
            *(uint4*)&ws[r * LDT + c8 * 8] = v;
        }
    }
    {
        const float4* X4 = (const float4*)X;
        #pragma unroll
        for (int it = 0; it < 8; ++it) {
            int idx = tid + it * 256;
            int r = idx >> 5, c4 = idx & 31;
            int row = row0 + r;
            float4 v = make_float4(0.f, 0.f, 0.f, 0.f);
            if (row < nrows) v = X4[(size_t)row * 32 + c4];
            ushort4 o;
            o.x = f2bf(v.x); o.y = f2bf(v.y); o.z = f2bf(v.z); o.w = f2bf(v.w);
            *(ushort4*)&xs[r * LDT + c4 * 4] = o;
        }
    }
    __syncthreads();

    constexpr int NT = COUT / 16;
    f32x4 acc[NT];
    #pragma unroll
    for (int t = 0; t < NT; ++t) acc[t] = (f32x4)(0.f);

    int arow = wave * 16 + (lane & 15);
    int khi  = (lane >> 4) * 8;

    #pragma unroll
    for (int kk = 0; kk < 4; ++kk) {
        bf16x8 a = *(const bf16x8*)&xs[arow * LDT + kk * 32 + khi];
        #pragma unroll
        for (int t = 0; t < NT; ++t) {
            bf16x8 b = *(const bf16x8*)&ws[(t * 16 + (lane & 15)) * LDT + kk * 32 + khi];
            acc[t] = __builtin_amdgcn_mfma_f32_16x16x32_bf16(a, b, acc[t], 0, 0, 0);
        }
    }

    int crow0 = (lane >> 4) * 4;
    int ccol  = lane & 15;
    #pragma unroll
    for (int t = 0; t < NT; ++t) {
        int col = t * 16 + ccol;
        float tw = tW[col];
        #pragma unroll
        for (int r = 0; r < 4; ++r) {
            int row = row0 + wave * 16 + crow0 + r;
            if (row < nrows)
                T[(size_t)row * COUT + col] = f2bf(acc[t][r] + tw);
        }
    }
}

#define GACC(vv, cc)                                                     \
    {                                                                    \
        float _f0, _f1;                                                  \
        unpack2(vv.x, _f0, _f1); acc[0] += _f0 * cc; acc[1] += _f1 * cc; \
        unpack2(vv.y, _f0, _f1); acc[2] += _f0 * cc; acc[3] += _f1 * cc; \
        unpack2(vv.z, _f0, _f1); acc[4] += _f0 * cc; acc[5] += _f1 * cc; \
        unpack2(vv.w, _f0, _f1); acc[6] += _f0 * cc; acc[7] += _f1 * cc; \
    }

// one edge from a scalar int2
#define GEDGE1(pp)                                                       \
    {                                                                    \
        uint4 _v = T4[(size_t)(pp).x * LPN + lane];                      \
        float _c = __int_as_float((pp).y);                               \
        GACC(_v, _c);                                                    \
    }

// ================ fused: gather(layer i) + relu + GEMM(layer i+1) ================
template<int COUT>
__global__ __launch_bounds__(1024, 8) void fused_gather_gemm_kernel(
    const unsigned short* __restrict__ Tin, const float* __restrict__ dinv,
    const int2* __restrict__ rng, const int2* __restrict__ csr,
    const float* __restrict__ bias, float* __restrict__ res,
    const unsigned short* __restrict__ Wt, const float* __restrict__ tW,
    unsigned short* __restrict__ Tout, int n)
{
    constexpr int LDT = 136;
    constexpr int LPN = 16;
    __shared__ unsigned short xs[64 * LDT];
    __shared__ unsigned short ws[COUT * LDT];

    int tid  = threadIdx.x;
    int row0 = blockIdx.x * 64;

    // stage W early (independent of gather)
    {
        const uint4* src = (const uint4*)Wt;          // COUT*16 uint4
        #pragma unroll
        for (int it = 0; it < COUT / 64; ++it) {
            int idx = tid + it * 1024;
            int r = idx >> 4, c8 = idx & 15;
            uint4 v = src[idx];
            *(uint4*)&ws[r * LDT + c8 * 8] = v;
        }
    }

    // ---- phase A: gather (16 lanes per node, 64 nodes per block) ----
    int lr   = tid >> 4;            // local row 0..63
    int node = row0 + lr;
    int lane = tid & 15;
    {
        float acc[8];
        if (node < n) {
            const uint4* T4 = (const uint4*)Tin;
            float di  = dinv[node];
            float cf0 = di * di;
            {
                uint4 tv = T4[(size_t)node * 16 + lane];
                float f[8];
                unpack2(tv.x, f[0], f[1]); unpack2(tv.y, f[2], f[3]);
                unpack2(tv.z, f[4], f[5]); unpack2(tv.w, f[6], f[7]);
                float4 b0 = ((const float4*)bias)[lane * 2];
                float4 b1 = ((const float4*)bias)[lane * 2 + 1];
                acc[0] = f[0] * cf0 + b0.x; acc[1] = f[1] * cf0 + b0.y;
                acc[2] = f[2] * cf0 + b0.z; acc[3] = f[3] * cf0 + b0.w;
                acc[4] = f[4] * cf0 + b1.x; acc[5] = f[5] * cf0 + b1.y;
                acc[6] = f[6] * cf0 + b1.z; acc[7] = f[7] * cf0 + b1.w;
            }
            int2 r = rng[node];
            int e = r.x, en = r.y;
            if ((e & 1) && e < en) {           // peel to even for 16B-aligned pairs
                int2 p0 = csr[e];
                GEDGE1(p0);
                ++e;
            }
            for (; e + 3 < en; e += 4) {       // 4 edges via two uint4 loads
                uint4 q0 = *(const uint4*)&csr[e];
                uint4 q1 = *(const uint4*)&csr[e + 2];
                uint4 v0 = T4[(size_t)(int)q0.x * LPN + lane];
                uint4 v1 = T4[(size_t)(int)q0.z * LPN + lane];
                uint4 v2 = T4[(size_t)(int)q1.x * LPN + lane];
                uint4 v3 = T4[(size_t)(int)q1.z * LPN + lane];
                float c0 = __uint_as_float(q0.y), c1 = __uint_as_float(q0.w);
                float c2 = __uint_as_float(q1.y), c3 = __uint_as_float(q1.w);
                GACC(v0, c0); GACC(v1, c1); GACC(v2, c2); GACC(v3, c3);
            }
            if (e + 1 < en) {                  // pair tail
                uint4 q0 = *(const uint4*)&csr[e];
                uint4 v0 = T4[(size_t)(int)q0.x * LPN + lane];
                uint4 v1 = T4[(size_t)(int)q0.z * LPN + lane];
                float c0 = __uint_as_float(q0.y), c1 = __uint_as_float(q0.w);
                GACC(v0, c0); GACC(v1, c1);
                e += 2;
            }
            if (e < en) {                      // single tail
                int2 p0 = csr[e];
                GEDGE1(p0);
            }
            #pragma unroll
            for (int j = 0; j < 8; ++j) acc[j] = fmaxf(acc[j], 0.f);   // relu

            float4 o0, o1;
            o0.x = acc[0]; o0.y = acc[1]; o0.z = acc[2]; o0.w = acc[3];
            o1.x = acc[4]; o1.y = acc[5]; o1.z = acc[6]; o1.w = acc[7];
            ((float4*)res)[(size_t)node * 32 + lane * 2]     = o0;
            ((float4*)res)[(size_t)node * 32 + lane * 2 + 1] = o1;
        } else {
            #pragma unroll
            for (int j = 0; j < 8; ++j) acc[j] = 0.f;
        }
        ushort4 h0, h1;
        h0.x = f2bf(acc[0]); h0.y = f2bf(acc[1]); h0.z = f2bf(acc[2]); h0.w = f2bf(acc[3]);
        h1.x = f2bf(acc[4]); h1.y = f2bf(acc[5]); h1.z = f2bf(acc[6]); h1.w = f2bf(acc[7]);
        *(ushort4*)&xs[lr * LDT + lane * 8]     = h0;
        *(ushort4*)&xs[lr * LDT + lane * 8 + 4] = h1;
    }
    __syncthreads();

    // ---- phase B: MFMA across 16 waves ----
    constexpr int TPW = (COUT / 16) / 4;               // tiles per wave
    int wave = tid >> 6, lane64 = tid & 63;
    int rt  = wave & 3;                                // row tile 0..3
    int ct0 = (wave >> 2) * TPW;                       // first col tile

    f32x4 acc2[TPW];
    #pragma unroll
    for (int t = 0; t < TPW; ++t) acc2[t] = (f32x4)(0.f);

    int arow = rt * 16 + (lane64 & 15);
    int khi  = (lane64 >> 4) * 8;

    #pragma unroll
    for (int kk = 0; kk < 4; ++kk) {
        bf16x8 a = *(const bf16x8*)&xs[arow * LDT + kk * 32 + khi];
        #pragma unroll
        for (int t = 0; t < TPW; ++t) {
            bf16x8 b = *(const bf16x8*)&ws[((ct0 + t) * 16 + (lane64 & 15)) * LDT + kk * 32 + khi];
            acc2[t] = __builtin_amdgcn_mfma_f32_16x16x32_bf16(a, b, acc2[t], 0, 0, 0);
        }
    }

    int crow0 = (lane64 >> 4) * 4;
    int ccol  = lane64 & 15;
    #pragma unroll
    for (int t = 0; t < TPW; ++t) {
        int col = (ct0 + t) * 16 + ccol;
        float tw = tW[col];
        #pragma unroll
        for (int r = 0; r < 4; ++r) {
            int row = row0 + rt * 16 + crow0 + r;
            if (row < n)
                Tout[(size_t)row * COUT + col] = f2bf(acc2[t][r] + tw);
        }
    }
}

// ===== standalone gather (final layer, COUT=64, no relu) =====
template<int COUT, bool RELU>
__global__ __launch_bounds__(256) void gather_kernel(
    const unsigned short* __restrict__ T, const float* __restrict__ dinv,
    const int2* __restrict__ rng, const int2* __restrict__ csr,
    const float* __restrict__ bias, float* __restrict__ out, int n)
{
    constexpr int LPN = COUT / 8;
    int tid = blockIdx.x * 256 + threadIdx.x;
    int node = tid / LPN, lane = tid % LPN;
    if (node >= n) return;

    const uint4* T4 = (const uint4*)T;
    float di  = dinv[node];
    float cf0 = di * di;

    float acc[8];
    {
        uint4 tv = T4[(size_t)node * LPN + lane];
        float f[8];
        unpack2(tv.x, f[0], f[1]); unpack2(tv.y, f[2], f[3]);
        unpack2(tv.z, f[4], f[5]); unpack2(tv.w, f[6], f[7]);
        float4 b0 = ((const float4*)bias)[lane * 2];
        float4 b1 = ((const float4*)bias)[lane * 2 + 1];
        acc[0] = f[0] * cf0 + b0.x; acc[1] = f[1] * cf0 + b0.y;
        acc[2] = f[2] * cf0 + b0.z; acc[3] = f[3] * cf0 + b0.w;
        acc[4] = f[4] * cf0 + b1.x; acc[5] = f[5] * cf0 + b1.y;
        acc[6] = f[6] * cf0 + b1.z; acc[7] = f[7] * cf0 + b1.w;
    }

    int2 r = rng[node];
    int e = r.x, en = r.y;
    if ((e & 1) && e < en) {
        int2 p0 = csr[e];
        GEDGE1(p0);
        ++e;
    }
    for (; e + 3 < en; e += 4) {
        uint4 q0 = *(const uint4*)&csr[e];
        uint4 q1 = *(const uint4*)&csr[e + 2];
        uint4 v0 = T4[(size_t)(int)q0.x * LPN + lane];
        uint4 v1 = T4[(size_t)(int)q0.z * LPN + lane];
        uint4 v2 = T4[(size_t)(int)q1.x * LPN + lane];
        uint4 v3 = T4[(size_t)(int)q1.z * LPN + lane];
        float c0 = __uint_as_float(q0.y), c1 = __uint_as_float(q0.w);
        float c2 = __uint_as_float(q1.y), c3 = __uint_as_float(q1.w);
        GACC(v0, c0); GACC(v1, c1); GACC(v2, c2); GACC(v3, c3);
    }
    if (e + 1 < en) {
        uint4 q0 = *(const uint4*)&csr[e];
        uint4 v0 = T4[(size_t)(int)q0.x * LPN + lane];
        uint4 v1 = T4[(size_t)(int)q0.z * LPN + lane];
        float c0 = __uint_as_float(q0.y), c1 = __uint_as_float(q0.w);
        GACC(v0, c0); GACC(v1, c1);
        e += 2;
    }
    if (e < en) {
        int2 p0 = csr[e];
        GEDGE1(p0);
    }

    if (RELU) {
        #pragma unroll
        for (int j = 0; j < 8; ++j) acc[j] = fmaxf(acc[j], 0.f);
    }
    float4* O4 = (float4*)out;
    float4 o0, o1;
    o0.x = acc[0]; o0.y = acc[1]; o0.z = acc[2]; o0.w = acc[3];
    o1.x = acc[4]; o1.y = acc[5]; o1.z = acc[6]; o1.w = acc[7];
    O4[(size_t)node * LPN * 2 + lane * 2]     = o0;
    O4[(size_t)node * LPN * 2 + lane * 2 + 1] = o1;
}

extern "C" void kernel_launch(void* const* d_in, const int* in_sizes, int n_in,
                              void* d_out, int out_size, void* d_ws, size_t ws_size,
                              hipStream_t stream) {
    const float* x   = (const float*)d_in[0];
    const int*   ei  = (const int*)d_in[1];
    const float* W1  = (const float*)d_in[4];
    const float* b1  = (const float*)d_in[5];
    const float* Wm  = (const float*)d_in[6];
    const float* bm  = (const float*)d_in[7];
    const float* W2  = (const float*)d_in[8];
    const float* b2  = (const float*)d_in[9];

    float* out  = (float*)d_out;
    float* res1 = out + (size_t)N_NODES * DOUT;
    float* res2 = res1 + (size_t)N_NODES * HDIM;

    // ---- workspace layout (all chunk sizes are 16B multiples; csr is 16B-aligned) ----
    unsigned short* T   = (unsigned short*)d_ws;            // N*128 bf16 (T1)
    unsigned short* T2  = T + (size_t)N_NODES * HDIM;       // N*128 bf16 (T2/T3)
    unsigned short* wt1 = T2 + (size_t)N_NODES * HDIM;      // 128*128
    unsigned short* wtm = wt1 + 128 * HDIM;
    unsigned short* wt2 = wtm + 128 * HDIM;                 // 64*128
    float* dinv = (float*)(wt2 + DOUT * 128);               // N
    float* tW1  = dinv + N_NODES;
    float* tWm  = tW1 + 128;
    float* tW2  = tWm + 128;
    int*   cnt     = (int*)(tW2 + 64);                // N   (memset to 0)
    int*   aggflag = cnt + N_NODES;                   // 128 (memset to 0, with cnt)
    int*   off     = aggflag + 128;                   // N
    int*   rank    = off + N_NODES;                   // E
    int2*  rng     = (int2*)(rank + N_EDGES);         // N
    int2*  csr     = (int2*)(rng + N_NODES);          // E entries (8B each)

    int gE = (N_EDGES + 255) / 256;
    int gT = (N_NODES + 63) / 64;
    int nb = (N_NODES + 1023) / 1024;                 // 98 scan blocks

    // ---- prep ptrs
    PrepPtrs p;
    p.g[0] = (const float*)d_in[10]; p.b[0] = (const float*)d_in[11];
    p.m[0] = (const float*)d_in[12]; p.v[0] = (const float*)d_in[13];
    p.g[1] = (const float*)d_in[14]; p.b[1] = (const float*)d_in[15];
    p.m[1] = (const float*)d_in[16]; p.v[1] = (const float*)d_in[17];
    p.g[2] = (const float*)d_in[18]; p.b[2] = (const float*)d_in[19];
    p.m[2] = (const float*)d_in[20]; p.v[2] = (const float*)d_in[21];
    p.W[0] = W1; p.W[1] = Wm; p.W[2] = W2;
    p.tW[0] = tW1; p.tW[1] = tWm; p.tW[2] = tW2;
    p.wt[0] = wt1; p.wt[1] = wtm; p.wt[2] = wt2;

    // ---- CSR build + prep ----
    hipMemsetAsync(cnt, 0, (N_NODES + 128) * sizeof(int), stream);   // cnt + aggflag
    combo_prep_kernel<<<gE + 3 + 192, 256, 0, stream>>>(ei, cnt, rank, N_EDGES, gE, p);
    scan_fused_kernel<<<nb, 1024, 0, stream>>>(cnt, off, dinv, rng, aggflag, N_NODES);

    // ---- merged: CSR fill + layer-1 GEMM (independent work, overlapped) ----
    fill_gemm_kernel<128><<<gT + gE, 256, 0, stream>>>(
        ei, dinv, off, rank, csr, N_EDGES, gT, x, wt1, tW1, T, N_NODES);

    // ---- fused: gather(T1)->res1 + GEMM(Wm)->T2
    fused_gather_gemm_kernel<128><<<gT, 1024, 0, stream>>>(
        T, dinv, rng, csr, b1, res1, wtm, tWm, T2, N_NODES);

    // ---- fused: gather(T2)->res2 + GEMM(W2)->T3 (reuse T buffer)
    fused_gather_gemm_kernel<64><<<gT, 1024, 0, stream>>>(
        T2, dinv, rng, csr, bm, res2, wt2, tW2, T, N_NODES);

    // ---- final gather: T3 -> out (COUT=64, no relu)
    gather_kernel<64, false><<<(N_NODES * 8 + 255) / 256, 256, 0, stream>>>(
        T, dinv, rng, csr, b2, out, N_NODES);
}

// Round 13
// 189.424 us; speedup vs baseline: 1.0192x; 1.0192x over previous
//
#include <hip/hip_runtime.h>

#define N_NODES 100000
#define N_EDGES 640000
#define DIN 128
#define HDIM 128
#define DOUT 64

typedef __attribute__((ext_vector_type(4))) float f32x4;
typedef __attribute__((ext_vector_type(8))) short bf16x8;

// ---------- bf16 helpers ----------
__device__ inline unsigned short f2bf(float x) {
    unsigned u = __float_as_uint(x);
    unsigned r = (u + 0x7fffu + ((u >> 16) & 1u)) >> 16;   // RNE
    return (unsigned short)r;
}
__device__ inline void unpack2(unsigned u, float& f0, float& f1) {
    f0 = __uint_as_float(u << 16);
    f1 = __uint_as_float(u & 0xffff0000u);
}

struct PrepPtrs {
    const float *g[3], *b[3], *m[3], *v[3];
    const float *W[3];                         // weights f32 [128][COUT]
    float *tW[3];
    unsigned short *wt[3];                     // bf16 [COUT][128]
};

// ================ combo: edge-rank histogram + BN fold/tW + weight transform ================
__global__ void combo_prep_kernel(const int* __restrict__ ei, int* __restrict__ cnt,
                                  int* __restrict__ rank, int ne, int gE, PrepPtrs p) {
    int bid = blockIdx.x, tid = threadIdx.x;
    if (bid < gE) {
        int e = bid * 256 + tid;
        if (e < ne) rank[e] = atomicAdd(&cnt[ei[ne + e]], 1);
        return;
    }
    if (bid < gE + 3) {
        __shared__ float sh_s[128];
        int l = bid - gE;
        if (tid < 128) {
            float s  = p.g[l][tid] * rsqrtf(p.v[l][tid] + 1e-5f);
            sh_s[tid] = p.b[l][tid] - p.m[l][tid] * s;
        }
        __syncthreads();
        int cout = (l == 2) ? DOUT : HDIM;
        if (tid < cout) {
            float acc = 0.f;
            for (int k = 0; k < 128; ++k) acc += sh_s[k] * p.W[l][k * cout + tid];
            p.tW[l][tid] = acc;
        }
        return;
    }
    {
        int idx0 = bid - gE - 3;          // 64 blocks per layer
        int l = idx0 >> 6;
        int cout = (l == 2) ? DOUT : HDIM;
        int idx = (idx0 & 63) * 256 + tid;   // k*cout + c
        if (idx >= 128 * cout) return;
        int k = idx / cout, c = idx % cout;
        float sc = p.g[l][k] * rsqrtf(p.v[l][k] + 1e-5f);
        p.wt[l][c * 128 + k] = f2bf(p.W[l][idx] * sc);
    }
}

// ================= CSR scan =================
__global__ void scan_block_kernel(const int* __restrict__ cnt, int* __restrict__ off,
                                  int* __restrict__ bsums, int n) {
    __shared__ int sm[1024];
    int tid = threadIdx.x;
    int i = blockIdx.x * 1024 + tid;
    int v = (i < n) ? cnt[i] : 0;
    sm[tid] = v;
    __syncthreads();
    for (int d = 1; d < 1024; d <<= 1) {
        int t = (tid >= d) ? sm[tid - d] : 0;
        __syncthreads();
        sm[tid] += t;
        __syncthreads();
    }
    if (i < n) off[i] = sm[tid] - v;          // exclusive (local)
    if (tid == 1023) bsums[blockIdx.x] = sm[1023];
}

// finalize: off += prefix(bsums); rng = {start,end}; dinv
__global__ void scan_add_kernel(int* __restrict__ off, const int* __restrict__ bsums,
                                const int* __restrict__ cnt, float* __restrict__ dinv,
                                int2* __restrict__ rng, int n, int nb) {
    __shared__ int red[4];
    int tid = threadIdx.x;
    int b = blockIdx.x >> 2;                  // 1024-bucket index
    int pv = (tid < b) ? bsums[tid] : 0;
    #pragma unroll
    for (int o = 32; o > 0; o >>= 1) pv += __shfl_down(pv, o);
    if ((tid & 63) == 0) red[tid >> 6] = pv;
    __syncthreads();
    int base = red[0] + red[1] + red[2] + red[3];
    int i = blockIdx.x * 256 + tid;
    if (i < n) {
        int o = off[i] + base;
        int c = cnt[i];
        off[i] = o;
        rng[i] = make_int2(o, o + c);
        dinv[i] = rsqrtf((float)c + 1.0f);    // +1 self loop
    }
}

// ================ merged: CSR fill (atomic-free) + layer-1 MFMA GEMM ================
// blocks [0, gT):        T[N][128] = bf16(X) @ Wt^T + tW
// blocks [gT, gT+gE):    csr[off[d]+rank[e]] = {src, coef}
template<int COUT>
__global__ __launch_bounds__(256) void fill_gemm_kernel(
    const int* __restrict__ ei, const float* __restrict__ dinv,
    const int* __restrict__ off, const int* __restrict__ rank,
    int2* __restrict__ csr, int ne, int gT,
    const float* __restrict__ X, const unsigned short* __restrict__ Wt,
    const float* __restrict__ tW, unsigned short* __restrict__ T, int nrows)
{
    constexpr int LDT = 136;
    __shared__ unsigned short xs[64 * LDT];
    __shared__ unsigned short ws[COUT * LDT];

    int tid = threadIdx.x;

    if (blockIdx.x >= gT) {
        // ---- fill path (block-uniform branch) ----
        int e = (blockIdx.x - gT) * 256 + tid;
        if (e < ne) {
            int s = ei[e], d = ei[ne + e];
            int2 ent;
            ent.x = s;
            ent.y = __float_as_int(dinv[s] * dinv[d]);
            csr[off[d] + rank[e]] = ent;
        }
        return;
    }

    // ---- GEMM path ----
    int wave = tid >> 6, lane = tid & 63;
    int row0 = blockIdx.x * 64;

    {
        const uint4* src = (const uint4*)Wt;
        #pragma unroll
        for (int it = 0; it < COUT / 16; ++it) {
            int idx = tid + it * 256;
            int r = idx >> 4, c8 = idx & 15;
            uint4 v = src[idx];
            *(uint4*)&ws[r * LDT + c8 * 8] = v;
        }
    }
    {
        const float4* X4 = (const float4*)X;
        #pragma unroll
        for (int it = 0; it < 8; ++it) {
            int idx = tid + it * 256;
            int r = idx >> 5, c4 = idx & 31;
            int row = row0 + r;
            float4 v = make_float4(0.f, 0.f, 0.f, 0.f);
            if (row < nrows) v = X4[(size_t)row * 32 + c4];
            ushort4 o;
            o.x = f2bf(v.x); o.y = f2bf(v.y); o.z = f2bf(v.z); o.w = f2bf(v.w);
            *(ushort4*)&xs[r * LDT + c4 * 4] = o;
        }
    }
    __syncthreads();

    constexpr int NT = COUT / 16;
    f32x4 acc[NT];
    #pragma unroll
    for (int t = 0; t < NT; ++t) acc[t] = (f32x4)(0.f);

    int arow = wave * 16 + (lane & 15);
    int khi  = (lane >> 4) * 8;

    #pragma unroll
    for (int kk = 0; kk < 4; ++kk) {
        bf16x8 a = *(const bf16x8*)&xs[arow * LDT + kk * 32 + khi];
        #pragma unroll
        for (int t = 0; t < NT; ++t) {
            bf16x8 b = *(const bf16x8*)&ws[(t * 16 + (lane & 15)) * LDT + kk * 32 + khi];
            acc[t] = __builtin_amdgcn_mfma_f32_16x16x32_bf16(a, b, acc[t], 0, 0, 0);
        }
    }

    int crow0 = (lane >> 4) * 4;
    int ccol  = lane & 15;
    #pragma unroll
    for (int t = 0; t < NT; ++t) {
        int col = t * 16 + ccol;
        float tw = tW[col];
        #pragma unroll
        for (int r = 0; r < 4; ++r) {
            int row = row0 + wave * 16 + crow0 + r;
            if (row < nrows)
                T[(size_t)row * COUT + col] = f2bf(acc[t][r] + tw);
        }
    }
}

#define GACC(vv, cc)                                                     \
    {                                                                    \
        float _f0, _f1;                                                  \
        unpack2(vv.x, _f0, _f1); acc[0] += _f0 * cc; acc[1] += _f1 * cc; \
        unpack2(vv.y, _f0, _f1); acc[2] += _f0 * cc; acc[3] += _f1 * cc; \
        unpack2(vv.z, _f0, _f1); acc[4] += _f0 * cc; acc[5] += _f1 * cc; \
        unpack2(vv.w, _f0, _f1); acc[6] += _f0 * cc; acc[7] += _f1 * cc; \
    }

// one edge from a scalar int2
#define GEDGE1(pp)                                                       \
    {                                                                    \
        uint4 _v = T4[(size_t)(pp).x * LPN + lane];                      \
        float _c = __int_as_float((pp).y);                               \
        GACC(_v, _c);                                                    \
    }

// ================ fused: gather(layer i) + relu + GEMM(layer i+1) ================
template<int COUT>
__global__ __launch_bounds__(1024, 8) void fused_gather_gemm_kernel(
    const unsigned short* __restrict__ Tin, const float* __restrict__ dinv,
    const int2* __restrict__ rng, const int2* __restrict__ csr,
    const float* __restrict__ bias, float* __restrict__ res,
    const unsigned short* __restrict__ Wt, const float* __restrict__ tW,
    unsigned short* __restrict__ Tout, int n)
{
    constexpr int LDT = 136;
    constexpr int LPN = 16;
    __shared__ unsigned short xs[64 * LDT];
    __shared__ unsigned short ws[COUT * LDT];

    int tid  = threadIdx.x;
    int row0 = blockIdx.x * 64;

    // stage W early (independent of gather)
    {
        const uint4* src = (const uint4*)Wt;          // COUT*16 uint4
        #pragma unroll
        for (int it = 0; it < COUT / 64; ++it) {
            int idx = tid + it * 1024;
            int r = idx >> 4, c8 = idx & 15;
            uint4 v = src[idx];
            *(uint4*)&ws[r * LDT + c8 * 8] = v;
        }
    }

    // ---- phase A: gather (16 lanes per node, 64 nodes per block) ----
    int lr   = tid >> 4;            // local row 0..63
    int node = row0 + lr;
    int lane = tid & 15;
    {
        float acc[8];
        if (node < n) {
            const uint4* T4 = (const uint4*)Tin;
            float di  = dinv[node];
            float cf0 = di * di;
            {
                uint4 tv = T4[(size_t)node * 16 + lane];
                float f[8];
                unpack2(tv.x, f[0], f[1]); unpack2(tv.y, f[2], f[3]);
                unpack2(tv.z, f[4], f[5]); unpack2(tv.w, f[6], f[7]);
                float4 b0 = ((const float4*)bias)[lane * 2];
                float4 b1 = ((const float4*)bias)[lane * 2 + 1];
                acc[0] = f[0] * cf0 + b0.x; acc[1] = f[1] * cf0 + b0.y;
                acc[2] = f[2] * cf0 + b0.z; acc[3] = f[3] * cf0 + b0.w;
                acc[4] = f[4] * cf0 + b1.x; acc[5] = f[5] * cf0 + b1.y;
                acc[6] = f[6] * cf0 + b1.z; acc[7] = f[7] * cf0 + b1.w;
            }
            int2 r = rng[node];
            int e = r.x, en = r.y;
            if ((e & 1) && e < en) {           // peel to even for 16B-aligned pairs
                int2 p0 = csr[e];
                GEDGE1(p0);
                ++e;
            }
            for (; e + 3 < en; e += 4) {       // 4 edges via two uint4 loads
                uint4 q0 = *(const uint4*)&csr[e];
                uint4 q1 = *(const uint4*)&csr[e + 2];
                uint4 v0 = T4[(size_t)(int)q0.x * LPN + lane];
                uint4 v1 = T4[(size_t)(int)q0.z * LPN + lane];
                uint4 v2 = T4[(size_t)(int)q1.x * LPN + lane];
                uint4 v3 = T4[(size_t)(int)q1.z * LPN + lane];
                float c0 = __uint_as_float(q0.y), c1 = __uint_as_float(q0.w);
                float c2 = __uint_as_float(q1.y), c3 = __uint_as_float(q1.w);
                GACC(v0, c0); GACC(v1, c1); GACC(v2, c2); GACC(v3, c3);
            }
            if (e + 1 < en) {                  // pair tail
                uint4 q0 = *(const uint4*)&csr[e];
                uint4 v0 = T4[(size_t)(int)q0.x * LPN + lane];
                uint4 v1 = T4[(size_t)(int)q0.z * LPN + lane];
                float c0 = __uint_as_float(q0.y), c1 = __uint_as_float(q0.w);
                GACC(v0, c0); GACC(v1, c1);
                e += 2;
            }
            if (e < en) {                      // single tail
                int2 p0 = csr[e];
                GEDGE1(p0);
            }
            #pragma unroll
            for (int j = 0; j < 8; ++j) acc[j] = fmaxf(acc[j], 0.f);   // relu

            float4 o0, o1;
            o0.x = acc[0]; o0.y = acc[1]; o0.z = acc[2]; o0.w = acc[3];
            o1.x = acc[4]; o1.y = acc[5]; o1.z = acc[6]; o1.w = acc[7];
            ((float4*)res)[(size_t)node * 32 + lane * 2]     = o0;
            ((float4*)res)[(size_t)node * 32 + lane * 2 + 1] = o1;
        } else {
            #pragma unroll
            for (int j = 0; j < 8; ++j) acc[j] = 0.f;
        }
        ushort4 h0, h1;
        h0.x = f2bf(acc[0]); h0.y = f2bf(acc[1]); h0.z = f2bf(acc[2]); h0.w = f2bf(acc[3]);
        h1.x = f2bf(acc[4]); h1.y = f2bf(acc[5]); h1.z = f2bf(acc[6]); h1.w = f2bf(acc[7]);
        *(ushort4*)&xs[lr * LDT + lane * 8]     = h0;
        *(ushort4*)&xs[lr * LDT + lane * 8 + 4] = h1;
    }
    __syncthreads();

    // ---- phase B: MFMA across 16 waves ----
    constexpr int TPW = (COUT / 16) / 4;               // tiles per wave
    int wave = tid >> 6, lane64 = tid & 63;
    int rt  = wave & 3;                                // row tile 0..3
    int ct0 = (wave >> 2) * TPW;                       // first col tile

    f32x4 acc2[TPW];
    #pragma unroll
    for (int t = 0; t < TPW; ++t) acc2[t] = (f32x4)(0.f);

    int arow = rt * 16 + (lane64 & 15);
    int khi  = (lane64 >> 4) * 8;

    #pragma unroll
    for (int kk = 0; kk < 4; ++kk) {
        bf16x8 a = *(const bf16x8*)&xs[arow * LDT + kk * 32 + khi];
        #pragma unroll
        for (int t = 0; t < TPW; ++t) {
            bf16x8 b = *(const bf16x8*)&ws[((ct0 + t) * 16 + (lane64 & 15)) * LDT + kk * 32 + khi];
            acc2[t] = __builtin_amdgcn_mfma_f32_16x16x32_bf16(a, b, acc2[t], 0, 0, 0);
        }
    }

    int crow0 = (lane64 >> 4) * 4;
    int ccol  = lane64 & 15;
    #pragma unroll
    for (int t = 0; t < TPW; ++t) {
        int col = (ct0 + t) * 16 + ccol;
        float tw = tW[col];
        #pragma unroll
        for (int r = 0; r < 4; ++r) {
            int row = row0 + rt * 16 + crow0 + r;
            if (row < n)
                Tout[(size_t)row * COUT + col] = f2bf(acc2[t][r] + tw);
        }
    }
}

// ===== standalone gather (final layer, COUT=64, no relu) =====
template<int COUT, bool RELU>
__global__ __launch_bounds__(256) void gather_kernel(
    const unsigned short* __restrict__ T, const float* __restrict__ dinv,
    const int2* __restrict__ rng, const int2* __restrict__ csr,
    const float* __restrict__ bias, float* __restrict__ out, int n)
{
    constexpr int LPN = COUT / 8;
    int tid = blockIdx.x * 256 + threadIdx.x;
    int node = tid / LPN, lane = tid % LPN;
    if (node >= n) return;

    const uint4* T4 = (const uint4*)T;
    float di  = dinv[node];
    float cf0 = di * di;

    float acc[8];
    {
        uint4 tv = T4[(size_t)node * LPN + lane];
        float f[8];
        unpack2(tv.x, f[0], f[1]); unpack2(tv.y, f[2], f[3]);
        unpack2(tv.z, f[4], f[5]); unpack2(tv.w, f[6], f[7]);
        float4 b0 = ((const float4*)bias)[lane * 2];
        float4 b1 = ((const float4*)bias)[lane * 2 + 1];
        acc[0] = f[0] * cf0 + b0.x; acc[1] = f[1] * cf0 + b0.y;
        acc[2] = f[2] * cf0 + b0.z; acc[3] = f[3] * cf0 + b0.w;
        acc[4] = f[4] * cf0 + b1.x; acc[5] = f[5] * cf0 + b1.y;
        acc[6] = f[6] * cf0 + b1.z; acc[7] = f[7] * cf0 + b1.w;
    }

    int2 r = rng[node];
    int e = r.x, en = r.y;
    if ((e & 1) && e < en) {
        int2 p0 = csr[e];
        GEDGE1(p0);
        ++e;
    }
    for (; e + 3 < en; e += 4) {
        uint4 q0 = *(const uint4*)&csr[e];
        uint4 q1 = *(const uint4*)&csr[e + 2];
        uint4 v0 = T4[(size_t)(int)q0.x * LPN + lane];
        uint4 v1 = T4[(size_t)(int)q0.z * LPN + lane];
        uint4 v2 = T4[(size_t)(int)q1.x * LPN + lane];
        uint4 v3 = T4[(size_t)(int)q1.z * LPN + lane];
        float c0 = __uint_as_float(q0.y), c1 = __uint_as_float(q0.w);
        float c2 = __uint_as_float(q1.y), c3 = __uint_as_float(q1.w);
        GACC(v0, c0); GACC(v1, c1); GACC(v2, c2); GACC(v3, c3);
    }
    if (e + 1 < en) {
        uint4 q0 = *(const uint4*)&csr[e];
        uint4 v0 = T4[(size_t)(int)q0.x * LPN + lane];
        uint4 v1 = T4[(size_t)(int)q0.z * LPN + lane];
        float c0 = __uint_as_float(q0.y), c1 = __uint_as_float(q0.w);
        GACC(v0, c0); GACC(v1, c1);
        e += 2;
    }
    if (e < en) {
        int2 p0 = csr[e];
        GEDGE1(p0);
    }

    if (RELU) {
        #pragma unroll
        for (int j = 0; j < 8; ++j) acc[j] = fmaxf(acc[j], 0.f);
    }
    float4* O4 = (float4*)out;
    float4 o0, o1;
    o0.x = acc[0]; o0.y = acc[1]; o0.z = acc[2]; o0.w = acc[3];
    o1.x = acc[4]; o1.y = acc[5]; o1.z = acc[6]; o1.w = acc[7];
    O4[(size_t)node * LPN * 2 + lane * 2]     = o0;
    O4[(size_t)node * LPN * 2 + lane * 2 + 1] = o1;
}

extern "C" void kernel_launch(void* const* d_in, const int* in_sizes, int n_in,
                              void* d_out, int out_size, void* d_ws, size_t ws_size,
                              hipStream_t stream) {
    const float* x   = (const float*)d_in[0];
    const int*   ei  = (const int*)d_in[1];
    const float* W1  = (const float*)d_in[4];
    const float* b1  = (const float*)d_in[5];
    const float* Wm  = (const float*)d_in[6];
    const float* bm  = (const float*)d_in[7];
    const float* W2  = (const float*)d_in[8];
    const float* b2  = (const float*)d_in[9];

    float* out  = (float*)d_out;
    float* res1 = out + (size_t)N_NODES * DOUT;
    float* res2 = res1 + (size_t)N_NODES * HDIM;

    // ---- workspace layout (all chunk sizes are 16B multiples; csr is 16B-aligned) ----
    unsigned short* T   = (unsigned short*)d_ws;            // N*128 bf16 (T1)
    unsigned short* T2  = T + (size_t)N_NODES * HDIM;       // N*128 bf16 (T2/T3)
    unsigned short* wt1 = T2 + (size_t)N_NODES * HDIM;      // 128*128
    unsigned short* wtm = wt1 + 128 * HDIM;
    unsigned short* wt2 = wtm + 128 * HDIM;                 // 64*128
    float* dinv = (float*)(wt2 + DOUT * 128);               // N
    float* tW1  = dinv + N_NODES;
    float* tWm  = tW1 + 128;
    float* tW2  = tWm + 128;
    int*   cnt   = (int*)(tW2 + 64);                  // N (memset to 0)
    int*   off   = cnt + N_NODES;                     // N
    int*   bsums = off + N_NODES;                     // 128
    int*   rank  = bsums + 128;                       // E
    int2*  rng   = (int2*)(rank + N_EDGES);           // N
    int2*  csr   = (int2*)(rng + N_NODES);            // E entries (8B each)

    int gN = (N_NODES + 255) / 256;
    int gE = (N_EDGES + 255) / 256;
    int gT = (N_NODES + 63) / 64;
    int nb = (N_NODES + 1023) / 1024;

    // ---- prep ptrs
    PrepPtrs p;
    p.g[0] = (const float*)d_in[10]; p.b[0] = (const float*)d_in[11];
    p.m[0] = (const float*)d_in[12]; p.v[0] = (const float*)d_in[13];
    p.g[1] = (const float*)d_in[14]; p.b[1] = (const float*)d_in[15];
    p.m[1] = (const float*)d_in[16]; p.v[1] = (const float*)d_in[17];
    p.g[2] = (const float*)d_in[18]; p.b[2] = (const float*)d_in[19];
    p.m[2] = (const float*)d_in[20]; p.v[2] = (const float*)d_in[21];
    p.W[0] = W1; p.W[1] = Wm; p.W[2] = W2;
    p.tW[0] = tW1; p.tW[1] = tWm; p.tW[2] = tW2;
    p.wt[0] = wt1; p.wt[1] = wtm; p.wt[2] = wt2;

    // ---- CSR build + prep ----
    hipMemsetAsync(cnt, 0, N_NODES * sizeof(int), stream);
    combo_prep_kernel<<<gE + 3 + 192, 256, 0, stream>>>(ei, cnt, rank, N_EDGES, gE, p);
    scan_block_kernel<<<nb, 1024, 0, stream>>>(cnt, off, bsums, N_NODES);
    scan_add_kernel<<<gN, 256, 0, stream>>>(off, bsums, cnt, dinv, rng, N_NODES, nb);

    // ---- merged: CSR fill + layer-1 GEMM (independent work, overlapped) ----
    fill_gemm_kernel<128><<<gT + gE, 256, 0, stream>>>(
        ei, dinv, off, rank, csr, N_EDGES, gT, x, wt1, tW1, T, N_NODES);

    // ---- fused: gather(T1)->res1 + GEMM(Wm)->T2
    fused_gather_gemm_kernel<128><<<gT, 1024, 0, stream>>>(
        T, dinv, rng, csr, b1, res1, wtm, tWm, T2, N_NODES);

    // ---- fused: gather(T2)->res2 + GEMM(W2)->T3 (reuse T buffer)
    fused_gather_gemm_kernel<64><<<gT, 1024, 0, stream>>>(
        T2, dinv, rng, csr, bm, res2, wt2, tW2, T, N_NODES);

    // ---- final gather: T3 -> out (COUT=64, no relu)
    gather_kernel<64, false><<<(N_NODES * 8 + 255) / 256, 256, 0, stream>>>(
        T, dinv, rng, csr, b2, out, N_NODES);
}